// Round 6
// baseline (266.015 us; speedup 1.0000x reference)
//
#include <hip/hip_runtime.h>

#define F_SZ 32
#define D_SZ 128
#define FD   4096                 // F_SZ * D_SZ (elements per b-row of original feat)
#define NPAIR 496
#define LDZ  136                  // pair_gemm LDS row stride (shorts): 272B = 17*16B, aligned, 2-way banks
#define LDH  68                   // prep_z half-tile stride (shorts): 136B, 8B-aligned, 4-way write conflicts

typedef __bf16 bf16x8 __attribute__((ext_vector_type(8)));
typedef float floatx4 __attribute__((ext_vector_type(4)));

__device__ __forceinline__ unsigned short f2bf(float f) {
  unsigned u = __float_as_uint(f);
  u += 0x7fffu + ((u >> 16) & 1u);
  return (unsigned short)(u >> 16);
}
__device__ __forceinline__ float bf2f(unsigned short h) {
  return __uint_as_float(((unsigned)h) << 16);
}
__device__ __forceinline__ void decode_pair(int p, int& io, int& jo) {
  int i = 0;
  while (p >= F_SZ - 1 - i) { p -= F_SZ - 1 - i; ++i; }
  io = i; jo = i + 1 + p;
}

// ---------------- Pass 1 (merged): Zt + i-major bf16 features ----------------
// blocks [0, 992): Zt[pair][e][d] = bf16(gate(M[i][j][d][e])), d-half per block
// blocks [992, 1504): fbI[f][b][d] = bf16(feat[b][f][d])  -- b contiguous per f!
__global__ __launch_bounds__(256)
void prep(const float* __restrict__ mat, const float* __restrict__ feat,
          unsigned short* __restrict__ Zt, unsigned short* __restrict__ fbI) {
  const int t = threadIdx.x;
  if (blockIdx.x < 2 * NPAIR) {
    __shared__ unsigned short tile[128 * LDH];
    const int pair = blockIdx.x >> 1;
    const int yh = blockIdx.x & 1;            // d-half
    int i, j; decode_pair(pair, i, j);
    const float* zp = mat + (((size_t)i * F_SZ + j) << 14) + (size_t)yh * 64 * 128;
    #pragma unroll 8
    for (int it = 0; it < 32; ++it) {
      int idx = it * 256 + t;                 // e fastest -> coalesced 32KB contiguous read
      int dd = idx >> 7, e = idx & 127;
      float v = zp[idx];
      float s = 1.0f / (1.0f + __expf(-v));
      float z = fminf(1.0f, fmaxf(0.0f, fmaf(s, 1.2f, -0.1f)));
      tile[e * LDH + dd] = f2bf(z);           // transposed store (4-way conflict w/ pad 68)
    }
    __syncthreads();
    unsigned short* op = Zt + ((size_t)pair << 14) + yh * 64;
    #pragma unroll
    for (int it = 0; it < 8; ++it) {
      int idx4 = it * 256 + t;                // 2048 ushort4 chunks
      int e = idx4 >> 4, d4 = idx4 & 15;
      *(ushort4*)&op[e * 128 + d4 * 4] = *(const ushort4*)&tile[e * LDH + d4 * 4];
    }
  } else {
    const int blk = blockIdx.x - 2 * NPAIR;   // 0..511
    #pragma unroll
    for (int it = 0; it < 8; ++it) {
      size_t g = (size_t)blk * 2048 + it * 256 + t;   // ushort4 index over [f][b][d4]
      int f = (int)(g >> 15), b = (int)((g >> 5) & 1023), d4 = (int)(g & 31);
      float4 v = ((const float4*)feat)[(size_t)b * 1024 + f * 32 + d4];
      ushort4 h;
      h.x = f2bf(v.x); h.y = f2bf(v.y); h.z = f2bf(v.z); h.w = f2bf(v.w);
      *(ushort4*)(fbI + g * 4) = h;           // fully contiguous write
    }
  }
}

// ---------------- Pass 2: one block per (pair, 256-b tile) ----------------
// Yt = Zt x(MFMA) fi^T. A = Zt tile in padded LDS (staged from L3-resident Zt);
// B = fi rows direct from fbI (contiguous region: 16-lane frag spans 4KB, 1 page).
// Wave tile 32b x 128e; no cross-wave combine; single barrier.
// C/D layout (verified r1-r5): col(lane&15)=b, row(quad*4+reg)=e.
__global__ __launch_bounds__(256, 4)
void pair_gemm(const unsigned short* __restrict__ Zt,
               const unsigned short* __restrict__ fbI,
               float* __restrict__ out) {
  __shared__ unsigned short sZ[128 * LDZ];
  int i, j; decode_pair(blockIdx.x, i, j);
  const int t = threadIdx.x;
  const int lane = t & 63, l15 = lane & 15, quad = lane >> 4;
  const int w = t >> 6;

  // ---- stage Zt tile (32KB contiguous, L3-hot): 8 uint4/thread, 2-way-free LDS writes ----
  {
    const unsigned short* zp = Zt + ((size_t)blockIdx.x << 14);
    #pragma unroll
    for (int r = 0; r < 8; ++r) {
      int s = r * 256 + t;                    // 16B-chunk slot 0..2047
      int row = s >> 4, c = s & 15;
      uint4 v = *(const uint4*)(zp + s * 8);
      *(uint4*)&sZ[row * LDZ + c * 8] = v;
    }
  }
  __syncthreads();

  const unsigned short* fbi = fbI + ((size_t)i << 17);   // i's [b][d] plane, 256KB contiguous
  const unsigned short* fbj = fbI + ((size_t)j << 17);

  #pragma unroll 1
  for (int itb = 0; itb < 2; ++itb) {
    const int rowbase = blockIdx.y * 256 + itb * 128 + w * 32;

    // B (fi) fragments: rows 256B apart inside a contiguous plane
    const unsigned short* fbp0 = fbi + (size_t)(rowbase + l15) * D_SZ + quad * 8;
    bf16x8 B0[4], B1[4];
    #pragma unroll
    for (int ks = 0; ks < 4; ++ks) {
      B0[ks] = *(const bf16x8*)(fbp0 + ks * 32);
      B1[ks] = *(const bf16x8*)(fbp0 + 16 * D_SZ + ks * 32);
    }

    floatx4 acc[8][2];
    #pragma unroll
    for (int mf = 0; mf < 8; ++mf) {
      acc[mf][0] = (floatx4){0.f, 0.f, 0.f, 0.f};
      acc[mf][1] = (floatx4){0.f, 0.f, 0.f, 0.f};
    }

    #pragma unroll
    for (int ks = 0; ks < 4; ++ks)
      #pragma unroll
      for (int mf = 0; mf < 8; ++mf) {
        bf16x8 A = *(const bf16x8*)&sZ[(mf * 16 + l15) * LDZ + ks * 32 + quad * 8];
        acc[mf][0] = __builtin_amdgcn_mfma_f32_16x16x32_bf16(A, B0[ks], acc[mf][0], 0, 0, 0);
        acc[mf][1] = __builtin_amdgcn_mfma_f32_16x16x32_bf16(A, B1[ks], acc[mf][1], 0, 0, 0);
      }

    // ---- epilogue: out[b,i,j] = sum_e Yt[e,b]*fj[b,e]; e = mf*16 + quad*4 + r ----
    #pragma unroll
    for (int nf = 0; nf < 2; ++nf) {
      const int b = rowbase + nf * 16 + l15;
      const unsigned short* fjp = fbj + (size_t)b * D_SZ + quad * 4;
      float pl = 0.f;
      #pragma unroll
      for (int mf = 0; mf < 8; ++mf) {
        ushort4 fh = *(const ushort4*)(fjp + mf * 16);
        floatx4 c = acc[mf][nf];
        pl = fmaf(c[0], bf2f(fh.x), pl);
        pl = fmaf(c[1], bf2f(fh.y), pl);
        pl = fmaf(c[2], bf2f(fh.z), pl);
        pl = fmaf(c[3], bf2f(fh.w), pl);
      }
      pl += __shfl_xor(pl, 16, 64);
      pl += __shfl_xor(pl, 32, 64);
      if (quad == 0)
        out[(size_t)b * (F_SZ * F_SZ) + i * F_SZ + j] = pl;
    }
  }
}

// ---------------- Fallback (round-1 kernel, needs no workspace) ----------------
#define LDA  136
#define LDB  136
__global__ __launch_bounds__(256, 2)
void interaction_pair_kernel(const float* __restrict__ feat,
                             const float* __restrict__ mat,
                             float* __restrict__ out) {
  __shared__ unsigned short sA[128 * LDA];
  __shared__ unsigned short sBT[128 * LDB];
  const int t = threadIdx.x;
  const int w = t >> 6, lane = t & 63, l15 = lane & 15, quad = lane >> 4;
  int i, j; decode_pair(blockIdx.x, i, j);
  {
    const float* zp = mat + (((size_t)i * F_SZ + j) << 14);
    #pragma unroll 8
    for (int it = 0; it < 64; ++it) {
      int idx = it * 256 + t;
      int d = idx >> 7, e = idx & 127;
      float v = zp[idx];
      float s = 1.0f / (1.0f + __expf(-v));
      float z = fminf(1.0f, fmaxf(0.0f, fmaf(s, 1.2f, -0.1f)));
      sBT[e * LDB + d] = f2bf(z);
    }
  }
  for (int bt = 0; bt < 8; ++bt) {
    const int b0 = bt * 128;
    #pragma unroll 4
    for (int it = 0; it < 16; ++it) {
      int idx4 = it * 256 + t;
      int r = idx4 >> 5, c4 = idx4 & 31;
      const float4 v = *(const float4*)(feat + (size_t)(b0 + r) * FD + i * D_SZ + c4 * 4);
      ushort4 h;
      h.x = f2bf(v.x); h.y = f2bf(v.y); h.z = f2bf(v.z); h.w = f2bf(v.w);
      *(ushort4*)(&sA[r * LDA + c4 * 4]) = h;
    }
    __syncthreads();
    floatx4 acc[2][8];
    #pragma unroll
    for (int mf = 0; mf < 2; ++mf)
      #pragma unroll
      for (int nf = 0; nf < 8; ++nf)
        acc[mf][nf] = (floatx4){0.f, 0.f, 0.f, 0.f};
    #pragma unroll
    for (int k0 = 0; k0 < 128; k0 += 32) {
      const int kc = k0 + quad * 8;
      bf16x8 a0 = *(const bf16x8*)&sA[(w * 32 +      l15) * LDA + kc];
      bf16x8 a1 = *(const bf16x8*)&sA[(w * 32 + 16 + l15) * LDA + kc];
      #pragma unroll
      for (int nf = 0; nf < 8; ++nf) {
        bf16x8 bfr = *(const bf16x8*)&sBT[(nf * 16 + l15) * LDB + kc];
        acc[0][nf] = __builtin_amdgcn_mfma_f32_16x16x32_bf16(a0, bfr, acc[0][nf], 0, 0, 0);
        acc[1][nf] = __builtin_amdgcn_mfma_f32_16x16x32_bf16(a1, bfr, acc[1][nf], 0, 0, 0);
      }
    }
    #pragma unroll
    for (int mf = 0; mf < 2; ++mf) {
      float pl[4] = {0.f, 0.f, 0.f, 0.f};
      const int rb = w * 32 + mf * 16 + quad * 4;
      #pragma unroll
      for (int nf = 0; nf < 8; ++nf) {
        const int col = nf * 16 + l15;
        const float* fj = feat + (size_t)(b0 + rb) * FD + j * D_SZ + col;
        floatx4 c = acc[mf][nf];
        pl[0] += c[0] * fj[0];
        pl[1] += c[1] * fj[FD];
        pl[2] += c[2] * fj[2 * FD];
        pl[3] += c[3] * fj[3 * FD];
      }
      #pragma unroll
      for (int off = 1; off < 16; off <<= 1) {
        pl[0] += __shfl_xor(pl[0], off, 64);
        pl[1] += __shfl_xor(pl[1], off, 64);
        pl[2] += __shfl_xor(pl[2], off, 64);
        pl[3] += __shfl_xor(pl[3], off, 64);
      }
      if (l15 == 0) {
        size_t ob = (size_t)(b0 + rb) * (F_SZ * F_SZ) + (size_t)i * F_SZ + j;
        out[ob]                   = pl[0];
        out[ob + 1 * F_SZ * F_SZ] = pl[1];
        out[ob + 2 * F_SZ * F_SZ] = pl[2];
        out[ob + 3 * F_SZ * F_SZ] = pl[3];
      }
    }
    __syncthreads();
  }
}

extern "C" void kernel_launch(void* const* d_in, const int* in_sizes, int n_in,
                              void* d_out, int out_size, void* d_ws, size_t ws_size,
                              hipStream_t stream) {
  const float* feat = (const float*)d_in[0];   // [B, F, D] fp32
  const float* mat  = (const float*)d_in[1];   // [F, F, D, D] fp32
  float* out = (float*)d_out;                  // [B, F, F] fp32

  hipMemsetAsync(out, 0, (size_t)out_size * sizeof(float), stream);

  const size_t zt_bytes = (size_t)NPAIR * D_SZ * D_SZ * sizeof(unsigned short);  // 16,252,928
  const size_t fb_bytes = (size_t)1024 * FD * sizeof(unsigned short);            //  8,388,608

  if (ws_size >= zt_bytes + fb_bytes) {
    unsigned short* Zt  = (unsigned short*)d_ws;
    unsigned short* fbI = Zt + (size_t)NPAIR * D_SZ * D_SZ;
    prep<<<dim3(2 * NPAIR + 512), dim3(256), 0, stream>>>(mat, feat, Zt, fbI);
    pair_gemm<<<dim3(NPAIR, 4), dim3(256), 0, stream>>>(Zt, fbI, out);
  } else {
    interaction_pair_kernel<<<dim3(NPAIR), dim3(256), 0, stream>>>(feat, mat, out);
  }
}